// Round 4
// baseline (27773.141 us; speedup 1.0000x reference)
//
#include <hip/hip_runtime.h>
#include <math.h>

#define B_ 16
#define S_ 256
#define T_ 256
#define E_ 1024
#define H_ 512
#define G_ 1536
#define V_ 32000

typedef unsigned short u16;
typedef short short8 __attribute__((ext_vector_type(8)));
typedef float f32x4 __attribute__((ext_vector_type(4)));

__device__ inline u16 f2bf(float x) {
  union { float f; unsigned u; } a; a.f = x;
  unsigned r = a.u + 0x7fff + ((a.u >> 16) & 1);
  return (u16)(r >> 16);
}
__device__ inline float bf2f(u16 h) {
  union { unsigned u; float f; } a; a.u = ((unsigned)h) << 16;
  return a.f;
}

// ---------------- embedding gathers ----------------
__global__ __launch_bounds__(256) void k_embed_enc(const int* __restrict__ sen,
                                                   const float* __restrict__ emb,
                                                   float* __restrict__ out) {
  long row = blockIdx.x;
  int tid = threadIdx.x;
  long e = sen[row];
  float4 v = *(const float4*)(emb + e * E_ + tid * 4);
  *(float4*)(out + row * E_ + tid * 4) = v;
}

__global__ __launch_bounds__(256) void k_embed_dec(const int* __restrict__ zh,
                                                   const float* __restrict__ emb,
                                                   float* __restrict__ out) {
  long row = blockIdx.x;
  int b = (int)(row >> 8), t = (int)(row & 255);
  int tid = threadIdx.x;
  long e = (t == 0) ? (V_ - 2) : zh[b * T_ + t - 1];
  float4 v = *(const float4*)(emb + e * E_ + tid * 4);
  *(float4*)(out + row * E_ + tid * 4) = v;
}

// ---------------- batched 32x32 tiled transpose ----------------
__global__ __launch_bounds__(256) void k_transpose(const float* __restrict__ in,
                                                   float* __restrict__ out, int R, int C) {
  __shared__ float tile[32][33];
  long z = blockIdx.z;
  const float* inz = in + z * (long)R * C;
  float* outz = out + z * (long)R * C;
  int x = blockIdx.x * 32 + threadIdx.x;
  int y0 = blockIdx.y * 32;
#pragma unroll
  for (int i = threadIdx.y; i < 32; i += 8)
    tile[i][threadIdx.x] = inz[(long)(y0 + i) * C + x];
  __syncthreads();
  int xo = y0 + threadIdx.x;
#pragma unroll
  for (int i = threadIdx.y; i < 32; i += 8) {
    int yo = blockIdx.x * 32 + i;
    outz[(long)yo * R + xo] = tile[threadIdx.x][i];
  }
}

// ---------------- fp32 SGEMM (small attention GEMMs) ----------------
__global__ __launch_bounds__(256) void k_gemm_nt(
    const float* __restrict__ A, int lda, const float* __restrict__ A2, int lda2, int kSplit,
    const float* __restrict__ Bm, int ldb, const float* __restrict__ bias,
    float* __restrict__ C, int ldc, int K, long sA, long sB, long sC) {
  __shared__ float As[8][132];
  __shared__ float Bs[8][132];
  int z = blockIdx.z;
  A += z * sA;
  Bm += z * sB;
  C += z * sC;
  int tid = threadIdx.x;
  int bm = blockIdx.y * 128, bn = blockIdx.x * 128;
  int tx = tid & 15, ty = tid >> 4;
  int lr = tid >> 1, lc = (tid & 1) * 4;
  float acc[8][8] = {};
  for (int k0 = 0; k0 < K; k0 += 8) {
    int ka = k0 + lc;
    const float* ap;
    if (A2 != nullptr && ka >= kSplit)
      ap = A2 + (long)(bm + lr) * lda2 + (ka - kSplit);
    else
      ap = A + (long)(bm + lr) * lda + ka;
    float4 a4 = *(const float4*)ap;
    float4 b4 = *(const float4*)(Bm + (long)(bn + lr) * ldb + k0 + lc);
    As[lc + 0][lr] = a4.x; As[lc + 1][lr] = a4.y; As[lc + 2][lr] = a4.z; As[lc + 3][lr] = a4.w;
    Bs[lc + 0][lr] = b4.x; Bs[lc + 1][lr] = b4.y; Bs[lc + 2][lr] = b4.z; Bs[lc + 3][lr] = b4.w;
    __syncthreads();
#pragma unroll
    for (int kk = 0; kk < 8; kk++) {
      float ar[8], br[8];
      *(float4*)&ar[0] = *(const float4*)&As[kk][ty * 8];
      *(float4*)&ar[4] = *(const float4*)&As[kk][ty * 8 + 4];
      *(float4*)&br[0] = *(const float4*)&Bs[kk][tx * 8];
      *(float4*)&br[4] = *(const float4*)&Bs[kk][tx * 8 + 4];
#pragma unroll
      for (int i = 0; i < 8; i++)
#pragma unroll
        for (int j = 0; j < 8; j++) acc[i][j] += ar[i] * br[j];
    }
    __syncthreads();
  }
  float bv[8];
#pragma unroll
  for (int j = 0; j < 8; j++) bv[j] = bias ? bias[bn + tx * 8 + j] : 0.f;
#pragma unroll
  for (int i = 0; i < 8; i++) {
    float* cp = C + (long)(bm + ty * 8 + i) * ldc + bn + tx * 8;
    float4 o0, o1;
    o0.x = acc[i][0] + bv[0]; o0.y = acc[i][1] + bv[1];
    o0.z = acc[i][2] + bv[2]; o0.w = acc[i][3] + bv[3];
    o1.x = acc[i][4] + bv[4]; o1.y = acc[i][5] + bv[5];
    o1.z = acc[i][6] + bv[6]; o1.w = acc[i][7] + bv[7];
    *(float4*)cp = o0;
    *(float4*)(cp + 4) = o1;
  }
}

// ---------------- split-bf16 MFMA GEMM (fp32 in/out) ----------------
__global__ __launch_bounds__(256) void k_gemm_mfma_nt(
    const float* __restrict__ A, int lda, const float* __restrict__ A2, int lda2, int kSplit,
    const float* __restrict__ Bm, int ldb, const float* __restrict__ bias,
    float* __restrict__ C, int ldc, int K) {
  __shared__ u16 Ah[128][40];
  __shared__ u16 Al[128][40];
  __shared__ u16 Bh[128][40];
  __shared__ u16 Bl[128][40];
  int tid = threadIdx.x;
  int bm = blockIdx.y * 128, bn = blockIdx.x * 128;
  int wave = tid >> 6, lane = tid & 63;
  int wm = (wave >> 1) * 64, wn = (wave & 1) * 64;
  int srow = tid >> 1, scol = (tid & 1) * 16;
  int fr = lane & 15, fk = (lane >> 4) * 8, fq = lane >> 4;

  f32x4 acc[4][4] = {};

  for (int k0 = 0; k0 < K; k0 += 32) {
    {
      int ka = k0 + scol;
      const float* ap;
      if (A2 != nullptr && ka >= kSplit)
        ap = A2 + (long)(bm + srow) * lda2 + (ka - kSplit);
      else
        ap = A + (long)(bm + srow) * lda + ka;
      float va[16];
      *(float4*)&va[0] = *(const float4*)ap;
      *(float4*)&va[4] = *(const float4*)(ap + 4);
      *(float4*)&va[8] = *(const float4*)(ap + 8);
      *(float4*)&va[12] = *(const float4*)(ap + 12);
      u16 h[16], l[16];
#pragma unroll
      for (int i = 0; i < 16; i++) {
        u16 hh = f2bf(va[i]);
        h[i] = hh;
        l[i] = f2bf(va[i] - bf2f(hh));
      }
      *(short8*)&Ah[srow][scol] = *(short8*)&h[0];
      *(short8*)&Ah[srow][scol + 8] = *(short8*)&h[8];
      *(short8*)&Al[srow][scol] = *(short8*)&l[0];
      *(short8*)&Al[srow][scol + 8] = *(short8*)&l[8];
    }
    {
      const float* bp = Bm + (long)(bn + srow) * ldb + k0 + scol;
      float vb[16];
      *(float4*)&vb[0] = *(const float4*)bp;
      *(float4*)&vb[4] = *(const float4*)(bp + 4);
      *(float4*)&vb[8] = *(const float4*)(bp + 8);
      *(float4*)&vb[12] = *(const float4*)(bp + 12);
      u16 h[16], l[16];
#pragma unroll
      for (int i = 0; i < 16; i++) {
        u16 hh = f2bf(vb[i]);
        h[i] = hh;
        l[i] = f2bf(vb[i] - bf2f(hh));
      }
      *(short8*)&Bh[srow][scol] = *(short8*)&h[0];
      *(short8*)&Bh[srow][scol + 8] = *(short8*)&h[8];
      *(short8*)&Bl[srow][scol] = *(short8*)&l[0];
      *(short8*)&Bl[srow][scol + 8] = *(short8*)&l[8];
    }
    __syncthreads();
    short8 afh[4], afl[4];
#pragma unroll
    for (int mt = 0; mt < 4; mt++) {
      afh[mt] = *(const short8*)&Ah[wm + mt * 16 + fr][fk];
      afl[mt] = *(const short8*)&Al[wm + mt * 16 + fr][fk];
    }
#pragma unroll
    for (int nt = 0; nt < 4; nt++) {
      short8 bh = *(const short8*)&Bh[wn + nt * 16 + fr][fk];
      short8 bl = *(const short8*)&Bl[wn + nt * 16 + fr][fk];
#pragma unroll
      for (int mt = 0; mt < 4; mt++) {
        acc[mt][nt] = __builtin_amdgcn_mfma_f32_16x16x32_bf16(afh[mt], bh, acc[mt][nt], 0, 0, 0);
        acc[mt][nt] = __builtin_amdgcn_mfma_f32_16x16x32_bf16(afh[mt], bl, acc[mt][nt], 0, 0, 0);
        acc[mt][nt] = __builtin_amdgcn_mfma_f32_16x16x32_bf16(afl[mt], bh, acc[mt][nt], 0, 0, 0);
      }
    }
    __syncthreads();
  }
#pragma unroll
  for (int nt = 0; nt < 4; nt++) {
    int col = bn + wn + nt * 16 + fr;
    float bv = bias ? bias[col] : 0.f;
#pragma unroll
    for (int mt = 0; mt < 4; mt++) {
      int row = bm + wm + mt * 16 + fq * 4;
#pragma unroll
      for (int j = 0; j < 4; j++)
        C[(long)(row + j) * ldc + col] = acc[mt][nt][j] + bv;
    }
  }
}

// ---------------- persistent GRU layer: all 256 steps in one kernel ----------------
// grid = 128 blocks x 256 threads. Block owns 4 j's (j0 = blockIdx.x*4).
// thread: jj = tid>>6 (one j per wave), b = (tid>>2)&15, kq = tid&3 (k-quarter).
// Whh [1536][512] native layout (row = g*512+j). Weights slice cached in LDS.
// Per-step sync: agent-scope release stores of h, threadfence, barrier, block0
// fetch_add on cnt[t], spin until gridDim.x, barrier. Co-residency: 128 blocks,
// ~60KB LDS -> >=1 block/CU on 256 CUs, all resident => no deadlock.
#define WS_ 528   // (jj,g) weight block stride: 4*132
#define HS_ 536   // per-batch h stride: 4*132+8 (even 16B-group spread)
__global__ __launch_bounds__(256) void k_gru_layer(
    const float* __restrict__ xp, float* __restrict__ y,
    const float* __restrict__ Whh, const float* __restrict__ bhh,
    const float* __restrict__ hinit, long hbs, int* __restrict__ cnt) {
  __shared__ float wls[12 * WS_];
  __shared__ float hls[16 * HS_];
  __shared__ float bls[12];
  int tid = threadIdx.x;
  int j0 = blockIdx.x * 4;
  int jj = tid >> 6, b = (tid >> 2) & 15, kq = tid & 3;

  // ---- load weight slice (12 rows of 512) into LDS, once ----
  for (int r = 0; r < 12; r++) {
    int jjr = r / 3, g = r % 3;
    const float* src = Whh + (long)(g * 512 + j0 + jjr) * 512;
    int k = tid * 2;
    float2 v = *(const float2*)(src + k);
    int dst = r * WS_ + (k >> 7) * 132 + (k & 127);
    wls[dst] = v.x;
    wls[dst + 1] = v.y;
  }
  if (tid < 12) bls[tid] = bhh[(tid % 3) * 512 + j0 + tid / 3];

  int hbase = b * HS_ + kq * 132;
  int wb0 = (jj * 3 + 0) * WS_ + kq * 132;
  int wb1 = (jj * 3 + 1) * WS_ + kq * 132;
  int wb2 = (jj * 3 + 2) * WS_ + kq * 132;
  int j = j0 + jj;
  int hjj = b * HS_ + (j >> 7) * 132 + (j & 127);  // h_prev[b][j] in LDS

  for (int t = 0; t < 256; t++) {
    __syncthreads();  // protect hls from previous step's readers
    // ---- stage h(t-1) [16][512] into LDS (agent-coherent loads) ----
#pragma unroll
    for (int i = 0; i < 32; i++) {
      int flat = i * 256 + tid;
      int bb = flat >> 9, rem = flat & 511;
      const float* src = (t == 0) ? (hinit + (long)bb * hbs + rem)
                                  : (y + ((long)bb * 256 + (t - 1)) * 512 + rem);
      float v = __hip_atomic_load(src, __ATOMIC_RELAXED, __HIP_MEMORY_SCOPE_AGENT);
      hls[bb * HS_ + (rem >> 7) * 132 + (rem & 127)] = v;
    }
    __syncthreads();
    // ---- matvec: 3 gates x 128 MACs per thread ----
    float a0 = 0.f, a1 = 0.f, a2 = 0.f;
#pragma unroll 8
    for (int kc = 0; kc < 128; kc += 4) {
      float4 hv = *(const float4*)&hls[hbase + kc];
      float4 w0 = *(const float4*)&wls[wb0 + kc];
      float4 w1 = *(const float4*)&wls[wb1 + kc];
      float4 w2 = *(const float4*)&wls[wb2 + kc];
      a0 += hv.x * w0.x + hv.y * w0.y + hv.z * w0.z + hv.w * w0.w;
      a1 += hv.x * w1.x + hv.y * w1.y + hv.z * w1.z + hv.w * w1.w;
      a2 += hv.x * w2.x + hv.y * w2.y + hv.z * w2.z + hv.w * w2.w;
    }
    a0 += __shfl_xor(a0, 1); a0 += __shfl_xor(a0, 2);
    a1 += __shfl_xor(a1, 1); a1 += __shfl_xor(a1, 2);
    a2 += __shfl_xor(a2, 1); a2 += __shfl_xor(a2, 2);
    if (kq == 0) {
      const float* xpt = xp + ((long)b * 256 + t) * 1536;
      float xr = xpt[j], xz = xpt[j + 512], xn = xpt[j + 1024];
      float hr = a0 + bls[jj * 3 + 0];
      float hz = a1 + bls[jj * 3 + 1];
      float hn = a2 + bls[jj * 3 + 2];
      float r = 1.f / (1.f + __expf(-(xr + hr)));
      float z = 1.f / (1.f + __expf(-(xz + hz)));
      float n = tanhf(xn + r * hn);
      float hp = hls[hjj];
      float hv = (1.f - z) * n + z * hp;
      __hip_atomic_store(&y[((long)b * 256 + t) * 512 + j], hv,
                         __ATOMIC_RELEASE, __HIP_MEMORY_SCOPE_AGENT);
    }
    // ---- grid-wide arrive + spin ----
    __threadfence();   // drain this thread's stores to coherent point
    __syncthreads();
    if (tid == 0) {
      __hip_atomic_fetch_add(&cnt[t], 1, __ATOMIC_ACQ_REL, __HIP_MEMORY_SCOPE_AGENT);
      while (__hip_atomic_load(&cnt[t], __ATOMIC_ACQUIRE, __HIP_MEMORY_SCOPE_AGENT) <
             (int)gridDim.x) {}
    }
    __syncthreads();
  }
}

// ---------------- row softmax over 256 ----------------
__global__ __launch_bounds__(256) void k_softmax(float* __restrict__ p) {
  long row = blockIdx.x;
  int tid = threadIdx.x;
  float* pr = p + row * 256;
  float v = pr[tid];
  float m = v;
#pragma unroll
  for (int off = 32; off >= 1; off >>= 1) m = fmaxf(m, __shfl_xor(m, off));
  __shared__ float wmax[4];
  __shared__ float wsum[4];
  int wv = tid >> 6, ln = tid & 63;
  if (ln == 0) wmax[wv] = m;
  __syncthreads();
  m = fmaxf(fmaxf(wmax[0], wmax[1]), fmaxf(wmax[2], wmax[3]));
  float e = expf(v - m);
  float s = e;
#pragma unroll
  for (int off = 32; off >= 1; off >>= 1) s += __shfl_xor(s, off);
  if (ln == 0) wsum[wv] = s;
  __syncthreads();
  s = wsum[0] + wsum[1] + wsum[2] + wsum[3];
  pr[tid] = e / s;
}

extern "C" void kernel_launch(void* const* d_in, const int* in_sizes, int n_in,
                              void* d_out, int out_size, void* d_ws, size_t ws_size,
                              hipStream_t stream) {
  const int* en_sen = (const int*)d_in[0];
  const int* zh_sen = (const int*)d_in[1];
  const float* en_emb = (const float*)d_in[2];
  const float* zh_emb = (const float*)d_in[3];
  const float* h0 = (const float*)d_in[4];
  const float* Wih_e0 = (const float*)d_in[5];
  const float* Whh_e0 = (const float*)d_in[6];
  const float* bih_e0 = (const float*)d_in[7];
  const float* bhh_e0 = (const float*)d_in[8];
  const float* Wih_e1 = (const float*)d_in[9];
  const float* Whh_e1 = (const float*)d_in[10];
  const float* bih_e1 = (const float*)d_in[11];
  const float* bhh_e1 = (const float*)d_in[12];
  const float* Wih_d0 = (const float*)d_in[13];
  const float* Whh_d0 = (const float*)d_in[14];
  const float* bih_d0 = (const float*)d_in[15];
  const float* bhh_d0 = (const float*)d_in[16];
  const float* Wih_d1 = (const float*)d_in[17];
  const float* Whh_d1 = (const float*)d_in[18];
  const float* bih_d1 = (const float*)d_in[19];
  const float* bhh_d1 = (const float*)d_in[20];
  const float* fcW = (const float*)d_in[21];
  const float* fcb = (const float*)d_in[22];
  float* out = (float*)d_out;

  // FC inputs must not alias d_out -> d_ws (16 MiB, as validated in R1-R3).
  float* decOut = (float*)d_ws;
  float* ctx = decOut + 2097152;

  // d_out scratch: flags (4x256 ints) + buffers; all consumed before final FC.
  int* flags = (int*)d_out;            // 1024 ints = 4 KB
  float* bufE = (float*)d_out + 4096;  // ex / zx  [B*256*1024] (16B-aligned)
  float* xp = bufE + 4194304;          // [B*256*1536]
  float* bufY = xp + 6291456;          // y_e0 then y_d0
  float* enOut = bufY + 2097152;       // y_e1
  float* scT = enOut + 2097152;        // scores/attn [B,T,S]
  float* enOutT = scT + 1048576;       // [B,512,256]

  hipMemsetAsync(flags, 0, 1024 * sizeof(int), stream);

  dim3 tb(32, 8);

  // ---------------- encoder ----------------
  k_embed_enc<<<B_ * S_, 256, 0, stream>>>(en_sen, en_emb, bufE);
  k_gemm_mfma_nt<<<dim3(G_ / 128, (B_ * S_) / 128, 1), 256, 0, stream>>>(
      bufE, E_, nullptr, 0, E_, Wih_e0, E_, bih_e0, xp, G_, E_);
  k_gru_layer<<<128, 256, 0, stream>>>(xp, bufY, Whh_e0, bhh_e0, h0, (long)H_, flags);
  k_gemm_mfma_nt<<<dim3(G_ / 128, (B_ * S_) / 128, 1), 256, 0, stream>>>(
      bufY, H_, nullptr, 0, H_, Wih_e1, H_, bih_e1, xp, G_, H_);
  k_gru_layer<<<128, 256, 0, stream>>>(xp, enOut, Whh_e1, bhh_e1, h0 + B_ * H_, (long)H_,
                                       flags + 256);

  // ---------------- decoder ----------------
  k_embed_dec<<<B_ * T_, 256, 0, stream>>>(zh_sen, zh_emb, bufE);
  k_gemm_mfma_nt<<<dim3(G_ / 128, (B_ * T_) / 128, 1), 256, 0, stream>>>(
      bufE, E_, nullptr, 0, E_, Wih_d0, E_, bih_d0, xp, G_, E_);
  // init h = y_e0[:,255,:] in bufY; row 255 only read at t=0, overwritten at t=255
  k_gru_layer<<<128, 256, 0, stream>>>(xp, bufY, Whh_d0, bhh_d0, bufY + 255 * H_,
                                       (long)(256 * H_), flags + 512);
  k_gemm_mfma_nt<<<dim3(G_ / 128, (B_ * T_) / 128, 1), 256, 0, stream>>>(
      bufY, H_, nullptr, 0, H_, Wih_d1, H_, bih_d1, xp, G_, H_);
  k_gru_layer<<<128, 256, 0, stream>>>(xp, decOut, Whh_d1, bhh_d1, enOut + 255 * H_,
                                       (long)(256 * H_), flags + 768);

  // ---------------- attention ----------------
  k_gemm_nt<<<dim3(S_ / 128, T_ / 128, B_), 256, 0, stream>>>(
      decOut, H_, nullptr, 0, H_, enOut, H_, nullptr, scT, S_, H_,
      (long)T_ * H_, (long)S_ * H_, (long)T_ * S_);
  k_softmax<<<B_ * T_, 256, 0, stream>>>(scT);
  k_transpose<<<dim3(16, 8, B_), tb, 0, stream>>>(enOut, enOutT, 256, 512);
  k_gemm_nt<<<dim3(H_ / 128, T_ / 128, B_), 256, 0, stream>>>(
      scT, S_, nullptr, 0, S_, enOutT, S_, nullptr, ctx, H_, S_,
      (long)T_ * S_, (long)H_ * S_, (long)T_ * H_);

  // ---------------- final FC ----------------
  k_gemm_mfma_nt<<<dim3(V_ / 128, (B_ * T_) / 128, 1), 256, 0, stream>>>(
      decOut, H_, ctx, H_, H_, fcW, E_, fcb, out, V_, E_);
}

// Round 5
// 10232.448 us; speedup vs baseline: 2.7142x; 2.7142x over previous
//
#include <hip/hip_runtime.h>
#include <math.h>

#define B_ 16
#define S_ 256
#define T_ 256
#define E_ 1024
#define H_ 512
#define G_ 1536
#define V_ 32000

typedef unsigned short u16;
typedef short short8 __attribute__((ext_vector_type(8)));
typedef float f32x4 __attribute__((ext_vector_type(4)));

__device__ inline u16 f2bf(float x) {
  union { float f; unsigned u; } a; a.f = x;
  unsigned r = a.u + 0x7fff + ((a.u >> 16) & 1);
  return (u16)(r >> 16);
}
__device__ inline float bf2f(u16 h) {
  union { unsigned u; float f; } a; a.u = ((unsigned)h) << 16;
  return a.f;
}

// Coherent (MALL-level) 16B load: bypasses L1+L2, no cache maintenance.
// Caller MUST execute s_waitcnt vmcnt(0) before using the result.
__device__ inline f32x4 load_f4_coh(const float* p) {
  f32x4 v;
  asm volatile("global_load_dwordx4 %0, %1, off sc0 sc1" : "=v"(v) : "v"(p));
  return v;
}

// ---------------- embedding gathers ----------------
__global__ __launch_bounds__(256) void k_embed_enc(const int* __restrict__ sen,
                                                   const float* __restrict__ emb,
                                                   float* __restrict__ out) {
  long row = blockIdx.x;
  int tid = threadIdx.x;
  long e = sen[row];
  float4 v = *(const float4*)(emb + e * E_ + tid * 4);
  *(float4*)(out + row * E_ + tid * 4) = v;
}

__global__ __launch_bounds__(256) void k_embed_dec(const int* __restrict__ zh,
                                                   const float* __restrict__ emb,
                                                   float* __restrict__ out) {
  long row = blockIdx.x;
  int b = (int)(row >> 8), t = (int)(row & 255);
  int tid = threadIdx.x;
  long e = (t == 0) ? (V_ - 2) : zh[b * T_ + t - 1];
  float4 v = *(const float4*)(emb + e * E_ + tid * 4);
  *(float4*)(out + row * E_ + tid * 4) = v;
}

// ---------------- batched 32x32 tiled transpose ----------------
__global__ __launch_bounds__(256) void k_transpose(const float* __restrict__ in,
                                                   float* __restrict__ out, int R, int C) {
  __shared__ float tile[32][33];
  long z = blockIdx.z;
  const float* inz = in + z * (long)R * C;
  float* outz = out + z * (long)R * C;
  int x = blockIdx.x * 32 + threadIdx.x;
  int y0 = blockIdx.y * 32;
#pragma unroll
  for (int i = threadIdx.y; i < 32; i += 8)
    tile[i][threadIdx.x] = inz[(long)(y0 + i) * C + x];
  __syncthreads();
  int xo = y0 + threadIdx.x;
#pragma unroll
  for (int i = threadIdx.y; i < 32; i += 8) {
    int yo = blockIdx.x * 32 + i;
    outz[(long)yo * R + xo] = tile[threadIdx.x][i];
  }
}

// ---------------- fp32 SGEMM (small attention GEMMs) ----------------
__global__ __launch_bounds__(256) void k_gemm_nt(
    const float* __restrict__ A, int lda, const float* __restrict__ A2, int lda2, int kSplit,
    const float* __restrict__ Bm, int ldb, const float* __restrict__ bias,
    float* __restrict__ C, int ldc, int K, long sA, long sB, long sC) {
  __shared__ float As[8][132];
  __shared__ float Bs[8][132];
  int z = blockIdx.z;
  A += z * sA;
  Bm += z * sB;
  C += z * sC;
  int tid = threadIdx.x;
  int bm = blockIdx.y * 128, bn = blockIdx.x * 128;
  int tx = tid & 15, ty = tid >> 4;
  int lr = tid >> 1, lc = (tid & 1) * 4;
  float acc[8][8] = {};
  for (int k0 = 0; k0 < K; k0 += 8) {
    int ka = k0 + lc;
    const float* ap;
    if (A2 != nullptr && ka >= kSplit)
      ap = A2 + (long)(bm + lr) * lda2 + (ka - kSplit);
    else
      ap = A + (long)(bm + lr) * lda + ka;
    float4 a4 = *(const float4*)ap;
    float4 b4 = *(const float4*)(Bm + (long)(bn + lr) * ldb + k0 + lc);
    As[lc + 0][lr] = a4.x; As[lc + 1][lr] = a4.y; As[lc + 2][lr] = a4.z; As[lc + 3][lr] = a4.w;
    Bs[lc + 0][lr] = b4.x; Bs[lc + 1][lr] = b4.y; Bs[lc + 2][lr] = b4.z; Bs[lc + 3][lr] = b4.w;
    __syncthreads();
#pragma unroll
    for (int kk = 0; kk < 8; kk++) {
      float ar[8], br[8];
      *(float4*)&ar[0] = *(const float4*)&As[kk][ty * 8];
      *(float4*)&ar[4] = *(const float4*)&As[kk][ty * 8 + 4];
      *(float4*)&br[0] = *(const float4*)&Bs[kk][tx * 8];
      *(float4*)&br[4] = *(const float4*)&Bs[kk][tx * 8 + 4];
#pragma unroll
      for (int i = 0; i < 8; i++)
#pragma unroll
        for (int j = 0; j < 8; j++) acc[i][j] += ar[i] * br[j];
    }
    __syncthreads();
  }
  float bv[8];
#pragma unroll
  for (int j = 0; j < 8; j++) bv[j] = bias ? bias[bn + tx * 8 + j] : 0.f;
#pragma unroll
  for (int i = 0; i < 8; i++) {
    float* cp = C + (long)(bm + ty * 8 + i) * ldc + bn + tx * 8;
    float4 o0, o1;
    o0.x = acc[i][0] + bv[0]; o0.y = acc[i][1] + bv[1];
    o0.z = acc[i][2] + bv[2]; o0.w = acc[i][3] + bv[3];
    o1.x = acc[i][4] + bv[4]; o1.y = acc[i][5] + bv[5];
    o1.z = acc[i][6] + bv[6]; o1.w = acc[i][7] + bv[7];
    *(float4*)cp = o0;
    *(float4*)(cp + 4) = o1;
  }
}

// ---------------- split-bf16 MFMA GEMM (fp32 in/out) ----------------
__global__ __launch_bounds__(256) void k_gemm_mfma_nt(
    const float* __restrict__ A, int lda, const float* __restrict__ A2, int lda2, int kSplit,
    const float* __restrict__ Bm, int ldb, const float* __restrict__ bias,
    float* __restrict__ C, int ldc, int K) {
  __shared__ u16 Ah[128][40];
  __shared__ u16 Al[128][40];
  __shared__ u16 Bh[128][40];
  __shared__ u16 Bl[128][40];
  int tid = threadIdx.x;
  int bm = blockIdx.y * 128, bn = blockIdx.x * 128;
  int wave = tid >> 6, lane = tid & 63;
  int wm = (wave >> 1) * 64, wn = (wave & 1) * 64;
  int srow = tid >> 1, scol = (tid & 1) * 16;
  int fr = lane & 15, fk = (lane >> 4) * 8, fq = lane >> 4;

  f32x4 acc[4][4] = {};

  for (int k0 = 0; k0 < K; k0 += 32) {
    {
      int ka = k0 + scol;
      const float* ap;
      if (A2 != nullptr && ka >= kSplit)
        ap = A2 + (long)(bm + srow) * lda2 + (ka - kSplit);
      else
        ap = A + (long)(bm + srow) * lda + ka;
      float va[16];
      *(float4*)&va[0] = *(const float4*)ap;
      *(float4*)&va[4] = *(const float4*)(ap + 4);
      *(float4*)&va[8] = *(const float4*)(ap + 8);
      *(float4*)&va[12] = *(const float4*)(ap + 12);
      u16 h[16], l[16];
#pragma unroll
      for (int i = 0; i < 16; i++) {
        u16 hh = f2bf(va[i]);
        h[i] = hh;
        l[i] = f2bf(va[i] - bf2f(hh));
      }
      *(short8*)&Ah[srow][scol] = *(short8*)&h[0];
      *(short8*)&Ah[srow][scol + 8] = *(short8*)&h[8];
      *(short8*)&Al[srow][scol] = *(short8*)&l[0];
      *(short8*)&Al[srow][scol + 8] = *(short8*)&l[8];
    }
    {
      const float* bp = Bm + (long)(bn + srow) * ldb + k0 + scol;
      float vb[16];
      *(float4*)&vb[0] = *(const float4*)bp;
      *(float4*)&vb[4] = *(const float4*)(bp + 4);
      *(float4*)&vb[8] = *(const float4*)(bp + 8);
      *(float4*)&vb[12] = *(const float4*)(bp + 12);
      u16 h[16], l[16];
#pragma unroll
      for (int i = 0; i < 16; i++) {
        u16 hh = f2bf(vb[i]);
        h[i] = hh;
        l[i] = f2bf(vb[i] - bf2f(hh));
      }
      *(short8*)&Bh[srow][scol] = *(short8*)&h[0];
      *(short8*)&Bh[srow][scol + 8] = *(short8*)&h[8];
      *(short8*)&Bl[srow][scol] = *(short8*)&l[0];
      *(short8*)&Bl[srow][scol + 8] = *(short8*)&l[8];
    }
    __syncthreads();
    short8 afh[4], afl[4];
#pragma unroll
    for (int mt = 0; mt < 4; mt++) {
      afh[mt] = *(const short8*)&Ah[wm + mt * 16 + fr][fk];
      afl[mt] = *(const short8*)&Al[wm + mt * 16 + fr][fk];
    }
#pragma unroll
    for (int nt = 0; nt < 4; nt++) {
      short8 bh = *(const short8*)&Bh[wn + nt * 16 + fr][fk];
      short8 bl = *(const short8*)&Bl[wn + nt * 16 + fr][fk];
#pragma unroll
      for (int mt = 0; mt < 4; mt++) {
        acc[mt][nt] = __builtin_amdgcn_mfma_f32_16x16x32_bf16(afh[mt], bh, acc[mt][nt], 0, 0, 0);
        acc[mt][nt] = __builtin_amdgcn_mfma_f32_16x16x32_bf16(afh[mt], bl, acc[mt][nt], 0, 0, 0);
        acc[mt][nt] = __builtin_amdgcn_mfma_f32_16x16x32_bf16(afl[mt], bh, acc[mt][nt], 0, 0, 0);
      }
    }
    __syncthreads();
  }
#pragma unroll
  for (int nt = 0; nt < 4; nt++) {
    int col = bn + wn + nt * 16 + fr;
    float bv = bias ? bias[col] : 0.f;
#pragma unroll
    for (int mt = 0; mt < 4; mt++) {
      int row = bm + wm + mt * 16 + fq * 4;
#pragma unroll
      for (int j = 0; j < 4; j++)
        C[(long)(row + j) * ldc + col] = acc[mt][nt][j] + bv;
    }
  }
}

// ---------------- persistent GRU layer (v2 sync: relaxed sc1 + acked-store barrier) ----
// grid = 128 blocks x 256 threads. Block owns 4 j's. Whh slice (24 KB) in LDS.
// Per-step barrier: relaxed sc1 stores -> s_waitcnt vmcnt(0) -> s_barrier ->
// one relaxed fetch_add into 16 distributed counters -> 16 threads poll.
// NO acquire/release/threadfence => no buffer_wbl2/buffer_inv L2 maintenance.
#define WS_ 528
#define HS_ 536
#define NC_ 16
__global__ __launch_bounds__(256) void k_gru_layer(
    const float* __restrict__ xp, float* __restrict__ y,
    const float* __restrict__ Whh, const float* __restrict__ bhh,
    const float* __restrict__ hinit, long hbs, int* __restrict__ cnt) {
  __shared__ float wls[12 * WS_];
  __shared__ float hls[16 * HS_];
  __shared__ float bls[12];
  int tid = threadIdx.x;
  int j0 = blockIdx.x * 4;
  int jj = tid >> 6, b = (tid >> 2) & 15, kq = tid & 3;

  for (int r = 0; r < 12; r++) {
    int jjr = r / 3, g = r % 3;
    const float* src = Whh + (long)(g * 512 + j0 + jjr) * 512;
    int k = tid * 2;
    float2 v = *(const float2*)(src + k);
    int dst = r * WS_ + (k >> 7) * 132 + (k & 127);
    wls[dst] = v.x;
    wls[dst + 1] = v.y;
  }
  if (tid < 12) bls[tid] = bhh[(tid % 3) * 512 + j0 + tid / 3];

  int hbase = b * HS_ + kq * 132;
  int wb0 = (jj * 3 + 0) * WS_ + kq * 132;
  int wb1 = (jj * 3 + 1) * WS_ + kq * 132;
  int wb2 = (jj * 3 + 2) * WS_ + kq * 132;
  int j = j0 + jj;
  int hjj = b * HS_ + (j >> 7) * 132 + (j & 127);

  for (int t = 0; t < 256; t++) {
    __syncthreads();  // protect hls from previous step's readers
    // ---- stage h(t-1) [16][512] via coherent 16B loads ----
    f32x4 hv4[8];
#pragma unroll
    for (int i = 0; i < 8; i++) {
      int f4 = i * 256 + tid;          // 2048 float4 = 32 KB
      int bb = f4 >> 7, rem4 = f4 & 127;
      const float* src = (t == 0) ? (hinit + (long)bb * hbs + rem4 * 4)
                                  : (y + ((long)bb * 256 + (t - 1)) * 512 + rem4 * 4);
      hv4[i] = load_f4_coh(src);
    }
    asm volatile("s_waitcnt vmcnt(0)" ::: "memory");
    __builtin_amdgcn_sched_barrier(0);
#pragma unroll
    for (int i = 0; i < 8; i++) {
      int f4 = i * 256 + tid;
      int bb = f4 >> 7, rem = (f4 & 127) * 4;
      *(f32x4*)&hls[bb * HS_ + (rem >> 7) * 132 + (rem & 127)] = hv4[i];
    }
    __syncthreads();
    // ---- matvec: 3 gates x 128 MACs per thread ----
    float a0 = 0.f, a1 = 0.f, a2 = 0.f;
#pragma unroll 8
    for (int kc = 0; kc < 128; kc += 4) {
      float4 hv = *(const float4*)&hls[hbase + kc];
      float4 w0 = *(const float4*)&wls[wb0 + kc];
      float4 w1 = *(const float4*)&wls[wb1 + kc];
      float4 w2 = *(const float4*)&wls[wb2 + kc];
      a0 += hv.x * w0.x + hv.y * w0.y + hv.z * w0.z + hv.w * w0.w;
      a1 += hv.x * w1.x + hv.y * w1.y + hv.z * w1.z + hv.w * w1.w;
      a2 += hv.x * w2.x + hv.y * w2.y + hv.z * w2.z + hv.w * w2.w;
    }
    a0 += __shfl_xor(a0, 1); a0 += __shfl_xor(a0, 2);
    a1 += __shfl_xor(a1, 1); a1 += __shfl_xor(a1, 2);
    a2 += __shfl_xor(a2, 1); a2 += __shfl_xor(a2, 2);
    if (kq == 0) {
      const float* xpt = xp + ((long)b * 256 + t) * 1536;
      float xr = xpt[j], xz = xpt[j + 512], xn = xpt[j + 1024];
      float hr = a0 + bls[jj * 3 + 0];
      float hz = a1 + bls[jj * 3 + 1];
      float hn = a2 + bls[jj * 3 + 2];
      float r = 1.f / (1.f + __expf(-(xr + hr)));
      float z = 1.f / (1.f + __expf(-(xz + hz)));
      float n = tanhf(xn + r * hn);
      float hp = hls[hjj];
      float hv = (1.f - z) * n + z * hp;
      __hip_atomic_store(&y[((long)b * 256 + t) * 512 + j], hv,
                         __ATOMIC_RELAXED, __HIP_MEMORY_SCOPE_AGENT);
    }
    // ---- acked-store barrier (no cache maintenance) ----
    asm volatile("s_waitcnt vmcnt(0)" ::: "memory");  // own stores acked at MALL
    __syncthreads();                                   // all threads' stores acked
    if (tid == 0)
      __hip_atomic_fetch_add(&cnt[t * NC_ + (blockIdx.x & (NC_ - 1))], 1,
                             __ATOMIC_RELAXED, __HIP_MEMORY_SCOPE_AGENT);
    if (tid < NC_) {
      while (__hip_atomic_load(&cnt[t * NC_ + tid], __ATOMIC_RELAXED,
                               __HIP_MEMORY_SCOPE_AGENT) < (128 / NC_)) {
        __builtin_amdgcn_s_sleep(1);
      }
    }
    __syncthreads();
  }
}

// ---------------- row softmax over 256 ----------------
__global__ __launch_bounds__(256) void k_softmax(float* __restrict__ p) {
  long row = blockIdx.x;
  int tid = threadIdx.x;
  float* pr = p + row * 256;
  float v = pr[tid];
  float m = v;
#pragma unroll
  for (int off = 32; off >= 1; off >>= 1) m = fmaxf(m, __shfl_xor(m, off));
  __shared__ float wmax[4];
  __shared__ float wsum[4];
  int wv = tid >> 6, ln = tid & 63;
  if (ln == 0) wmax[wv] = m;
  __syncthreads();
  m = fmaxf(fmaxf(wmax[0], wmax[1]), fmaxf(wmax[2], wmax[3]));
  float e = expf(v - m);
  float s = e;
#pragma unroll
  for (int off = 32; off >= 1; off >>= 1) s += __shfl_xor(s, off);
  if (ln == 0) wsum[wv] = s;
  __syncthreads();
  s = wsum[0] + wsum[1] + wsum[2] + wsum[3];
  pr[tid] = e / s;
}

extern "C" void kernel_launch(void* const* d_in, const int* in_sizes, int n_in,
                              void* d_out, int out_size, void* d_ws, size_t ws_size,
                              hipStream_t stream) {
  const int* en_sen = (const int*)d_in[0];
  const int* zh_sen = (const int*)d_in[1];
  const float* en_emb = (const float*)d_in[2];
  const float* zh_emb = (const float*)d_in[3];
  const float* h0 = (const float*)d_in[4];
  const float* Wih_e0 = (const float*)d_in[5];
  const float* Whh_e0 = (const float*)d_in[6];
  const float* bih_e0 = (const float*)d_in[7];
  const float* bhh_e0 = (const float*)d_in[8];
  const float* Wih_e1 = (const float*)d_in[9];
  const float* Whh_e1 = (const float*)d_in[10];
  const float* bih_e1 = (const float*)d_in[11];
  const float* bhh_e1 = (const float*)d_in[12];
  const float* Wih_d0 = (const float*)d_in[13];
  const float* Whh_d0 = (const float*)d_in[14];
  const float* bih_d0 = (const float*)d_in[15];
  const float* bhh_d0 = (const float*)d_in[16];
  const float* Wih_d1 = (const float*)d_in[17];
  const float* Whh_d1 = (const float*)d_in[18];
  const float* bih_d1 = (const float*)d_in[19];
  const float* bhh_d1 = (const float*)d_in[20];
  const float* fcW = (const float*)d_in[21];
  const float* fcb = (const float*)d_in[22];
  float* out = (float*)d_out;

  // FC inputs must not alias d_out -> d_ws (16 MiB).
  float* decOut = (float*)d_ws;
  float* ctx = decOut + 2097152;

  // d_out scratch: flags [4][256][NC_] ints = 64 KB, then buffers.
  int* flags = (int*)d_out;              // 16384 ints
  float* bufE = (float*)d_out + 16384;   // ex / zx  [B*256*1024]
  float* xp = bufE + 4194304;            // [B*256*1536]
  float* bufY = xp + 6291456;            // y_e0 then y_d0
  float* enOut = bufY + 2097152;         // y_e1
  float* scT = enOut + 2097152;          // scores/attn [B,T,S]
  float* enOutT = scT + 1048576;         // [B,512,256]

  hipMemsetAsync(flags, 0, 16384 * sizeof(int), stream);

  dim3 tb(32, 8);

  // ---------------- encoder ----------------
  k_embed_enc<<<B_ * S_, 256, 0, stream>>>(en_sen, en_emb, bufE);
  k_gemm_mfma_nt<<<dim3(G_ / 128, (B_ * S_) / 128, 1), 256, 0, stream>>>(
      bufE, E_, nullptr, 0, E_, Wih_e0, E_, bih_e0, xp, G_, E_);
  k_gru_layer<<<128, 256, 0, stream>>>(xp, bufY, Whh_e0, bhh_e0, h0, (long)H_, flags);
  k_gemm_mfma_nt<<<dim3(G_ / 128, (B_ * S_) / 128, 1), 256, 0, stream>>>(
      bufY, H_, nullptr, 0, H_, Wih_e1, H_, bih_e1, xp, G_, H_);
  k_gru_layer<<<128, 256, 0, stream>>>(xp, enOut, Whh_e1, bhh_e1, h0 + B_ * H_, (long)H_,
                                       flags + 4096);

  // ---------------- decoder ----------------
  k_embed_dec<<<B_ * T_, 256, 0, stream>>>(zh_sen, zh_emb, bufE);
  k_gemm_mfma_nt<<<dim3(G_ / 128, (B_ * T_) / 128, 1), 256, 0, stream>>>(
      bufE, E_, nullptr, 0, E_, Wih_d0, E_, bih_d0, xp, G_, E_);
  k_gru_layer<<<128, 256, 0, stream>>>(xp, bufY, Whh_d0, bhh_d0, bufY + 255 * H_,
                                       (long)(256 * H_), flags + 8192);
  k_gemm_mfma_nt<<<dim3(G_ / 128, (B_ * T_) / 128, 1), 256, 0, stream>>>(
      bufY, H_, nullptr, 0, H_, Wih_d1, H_, bih_d1, xp, G_, H_);
  k_gru_layer<<<128, 256, 0, stream>>>(xp, decOut, Whh_d1, bhh_d1, enOut + 255 * H_,
                                       (long)(256 * H_), flags + 12288);

  // ---------------- attention ----------------
  k_gemm_nt<<<dim3(S_ / 128, T_ / 128, B_), 256, 0, stream>>>(
      decOut, H_, nullptr, 0, H_, enOut, H_, nullptr, scT, S_, H_,
      (long)T_ * H_, (long)S_ * H_, (long)T_ * S_);
  k_softmax<<<B_ * T_, 256, 0, stream>>>(scT);
  k_transpose<<<dim3(16, 8, B_), tb, 0, stream>>>(enOut, enOutT, 256, 512);
  k_gemm_nt<<<dim3(H_ / 128, T_ / 128, B_), 256, 0, stream>>>(
      scT, S_, nullptr, 0, S_, enOutT, S_, nullptr, ctx, H_, S_,
      (long)T_ * S_, (long)H_ * S_, (long)T_ * H_);

  // ---------------- final FC ----------------
  k_gemm_mfma_nt<<<dim3(V_ / 128, (B_ * T_) / 128, 1), 256, 0, stream>>>(
      decOut, H_, ctx, H_, H_, fcW, E_, fcb, out, V_, E_);
}

// Round 6
// 6701.120 us; speedup vs baseline: 4.1446x; 1.5270x over previous
//
#include <hip/hip_runtime.h>
#include <math.h>

#define B_ 16
#define S_ 256
#define T_ 256
#define E_ 1024
#define H_ 512
#define G_ 1536
#define V_ 32000

typedef unsigned short u16;
typedef short short8 __attribute__((ext_vector_type(8)));
typedef float f32x4 __attribute__((ext_vector_type(4)));

__device__ inline u16 f2bf(float x) {
  union { float f; unsigned u; } a; a.f = x;
  unsigned r = a.u + 0x7fff + ((a.u >> 16) & 1);
  return (u16)(r >> 16);
}
__device__ inline float bf2f(u16 h) {
  union { unsigned u; float f; } a; a.u = ((unsigned)h) << 16;
  return a.f;
}

// Coherent (MALL-level) 16B load: bypasses L1+L2, no cache maintenance.
// Caller MUST execute s_waitcnt vmcnt(0) before using the result.
__device__ inline f32x4 load_f4_coh(const float* p) {
  f32x4 v;
  asm volatile("global_load_dwordx4 %0, %1, off sc0 sc1" : "=v"(v) : "v"(p));
  return v;
}

// ---------------- embedding gathers ----------------
__global__ __launch_bounds__(256) void k_embed_enc(const int* __restrict__ sen,
                                                   const float* __restrict__ emb,
                                                   float* __restrict__ out) {
  long row = blockIdx.x;
  int tid = threadIdx.x;
  long e = sen[row];
  float4 v = *(const float4*)(emb + e * E_ + tid * 4);
  *(float4*)(out + row * E_ + tid * 4) = v;
}

__global__ __launch_bounds__(256) void k_embed_dec(const int* __restrict__ zh,
                                                   const float* __restrict__ emb,
                                                   float* __restrict__ out) {
  long row = blockIdx.x;
  int b = (int)(row >> 8), t = (int)(row & 255);
  int tid = threadIdx.x;
  long e = (t == 0) ? (V_ - 2) : zh[b * T_ + t - 1];
  float4 v = *(const float4*)(emb + e * E_ + tid * 4);
  *(float4*)(out + row * E_ + tid * 4) = v;
}

// ---------------- batched 32x32 tiled transpose ----------------
__global__ __launch_bounds__(256) void k_transpose(const float* __restrict__ in,
                                                   float* __restrict__ out, int R, int C) {
  __shared__ float tile[32][33];
  long z = blockIdx.z;
  const float* inz = in + z * (long)R * C;
  float* outz = out + z * (long)R * C;
  int x = blockIdx.x * 32 + threadIdx.x;
  int y0 = blockIdx.y * 32;
#pragma unroll
  for (int i = threadIdx.y; i < 32; i += 8)
    tile[i][threadIdx.x] = inz[(long)(y0 + i) * C + x];
  __syncthreads();
  int xo = y0 + threadIdx.x;
#pragma unroll
  for (int i = threadIdx.y; i < 32; i += 8) {
    int yo = blockIdx.x * 32 + i;
    outz[(long)yo * R + xo] = tile[threadIdx.x][i];
  }
}

// ---------------- fp32 SGEMM (small attention GEMMs) ----------------
__global__ __launch_bounds__(256) void k_gemm_nt(
    const float* __restrict__ A, int lda, const float* __restrict__ A2, int lda2, int kSplit,
    const float* __restrict__ Bm, int ldb, const float* __restrict__ bias,
    float* __restrict__ C, int ldc, int K, long sA, long sB, long sC) {
  __shared__ float As[8][132];
  __shared__ float Bs[8][132];
  int z = blockIdx.z;
  A += z * sA;
  Bm += z * sB;
  C += z * sC;
  int tid = threadIdx.x;
  int bm = blockIdx.y * 128, bn = blockIdx.x * 128;
  int tx = tid & 15, ty = tid >> 4;
  int lr = tid >> 1, lc = (tid & 1) * 4;
  float acc[8][8] = {};
  for (int k0 = 0; k0 < K; k0 += 8) {
    int ka = k0 + lc;
    const float* ap;
    if (A2 != nullptr && ka >= kSplit)
      ap = A2 + (long)(bm + lr) * lda2 + (ka - kSplit);
    else
      ap = A + (long)(bm + lr) * lda + ka;
    float4 a4 = *(const float4*)ap;
    float4 b4 = *(const float4*)(Bm + (long)(bn + lr) * ldb + k0 + lc);
    As[lc + 0][lr] = a4.x; As[lc + 1][lr] = a4.y; As[lc + 2][lr] = a4.z; As[lc + 3][lr] = a4.w;
    Bs[lc + 0][lr] = b4.x; Bs[lc + 1][lr] = b4.y; Bs[lc + 2][lr] = b4.z; Bs[lc + 3][lr] = b4.w;
    __syncthreads();
#pragma unroll
    for (int kk = 0; kk < 8; kk++) {
      float ar[8], br[8];
      *(float4*)&ar[0] = *(const float4*)&As[kk][ty * 8];
      *(float4*)&ar[4] = *(const float4*)&As[kk][ty * 8 + 4];
      *(float4*)&br[0] = *(const float4*)&Bs[kk][tx * 8];
      *(float4*)&br[4] = *(const float4*)&Bs[kk][tx * 8 + 4];
#pragma unroll
      for (int i = 0; i < 8; i++)
#pragma unroll
        for (int j = 0; j < 8; j++) acc[i][j] += ar[i] * br[j];
    }
    __syncthreads();
  }
  float bv[8];
#pragma unroll
  for (int j = 0; j < 8; j++) bv[j] = bias ? bias[bn + tx * 8 + j] : 0.f;
#pragma unroll
  for (int i = 0; i < 8; i++) {
    float* cp = C + (long)(bm + ty * 8 + i) * ldc + bn + tx * 8;
    float4 o0, o1;
    o0.x = acc[i][0] + bv[0]; o0.y = acc[i][1] + bv[1];
    o0.z = acc[i][2] + bv[2]; o0.w = acc[i][3] + bv[3];
    o1.x = acc[i][4] + bv[4]; o1.y = acc[i][5] + bv[5];
    o1.z = acc[i][6] + bv[6]; o1.w = acc[i][7] + bv[7];
    *(float4*)cp = o0;
    *(float4*)(cp + 4) = o1;
  }
}

// ---------------- split-bf16 MFMA GEMM (fp32 in/out) ----------------
__global__ __launch_bounds__(256) void k_gemm_mfma_nt(
    const float* __restrict__ A, int lda, const float* __restrict__ A2, int lda2, int kSplit,
    const float* __restrict__ Bm, int ldb, const float* __restrict__ bias,
    float* __restrict__ C, int ldc, int K) {
  __shared__ u16 Ah[128][40];
  __shared__ u16 Al[128][40];
  __shared__ u16 Bh[128][40];
  __shared__ u16 Bl[128][40];
  int tid = threadIdx.x;
  int bm = blockIdx.y * 128, bn = blockIdx.x * 128;
  int wave = tid >> 6, lane = tid & 63;
  int wm = (wave >> 1) * 64, wn = (wave & 1) * 64;
  int srow = tid >> 1, scol = (tid & 1) * 16;
  int fr = lane & 15, fk = (lane >> 4) * 8, fq = lane >> 4;

  f32x4 acc[4][4] = {};

  for (int k0 = 0; k0 < K; k0 += 32) {
    {
      int ka = k0 + scol;
      const float* ap;
      if (A2 != nullptr && ka >= kSplit)
        ap = A2 + (long)(bm + srow) * lda2 + (ka - kSplit);
      else
        ap = A + (long)(bm + srow) * lda + ka;
      float va[16];
      *(float4*)&va[0] = *(const float4*)ap;
      *(float4*)&va[4] = *(const float4*)(ap + 4);
      *(float4*)&va[8] = *(const float4*)(ap + 8);
      *(float4*)&va[12] = *(const float4*)(ap + 12);
      u16 h[16], l[16];
#pragma unroll
      for (int i = 0; i < 16; i++) {
        u16 hh = f2bf(va[i]);
        h[i] = hh;
        l[i] = f2bf(va[i] - bf2f(hh));
      }
      *(short8*)&Ah[srow][scol] = *(short8*)&h[0];
      *(short8*)&Ah[srow][scol + 8] = *(short8*)&h[8];
      *(short8*)&Al[srow][scol] = *(short8*)&l[0];
      *(short8*)&Al[srow][scol + 8] = *(short8*)&l[8];
    }
    {
      const float* bp = Bm + (long)(bn + srow) * ldb + k0 + scol;
      float vb[16];
      *(float4*)&vb[0] = *(const float4*)bp;
      *(float4*)&vb[4] = *(const float4*)(bp + 4);
      *(float4*)&vb[8] = *(const float4*)(bp + 8);
      *(float4*)&vb[12] = *(const float4*)(bp + 12);
      u16 h[16], l[16];
#pragma unroll
      for (int i = 0; i < 16; i++) {
        u16 hh = f2bf(vb[i]);
        h[i] = hh;
        l[i] = f2bf(vb[i] - bf2f(hh));
      }
      *(short8*)&Bh[srow][scol] = *(short8*)&h[0];
      *(short8*)&Bh[srow][scol + 8] = *(short8*)&h[8];
      *(short8*)&Bl[srow][scol] = *(short8*)&l[0];
      *(short8*)&Bl[srow][scol + 8] = *(short8*)&l[8];
    }
    __syncthreads();
    short8 afh[4], afl[4];
#pragma unroll
    for (int mt = 0; mt < 4; mt++) {
      afh[mt] = *(const short8*)&Ah[wm + mt * 16 + fr][fk];
      afl[mt] = *(const short8*)&Al[wm + mt * 16 + fr][fk];
    }
#pragma unroll
    for (int nt = 0; nt < 4; nt++) {
      short8 bh = *(const short8*)&Bh[wn + nt * 16 + fr][fk];
      short8 bl = *(const short8*)&Bl[wn + nt * 16 + fr][fk];
#pragma unroll
      for (int mt = 0; mt < 4; mt++) {
        acc[mt][nt] = __builtin_amdgcn_mfma_f32_16x16x32_bf16(afh[mt], bh, acc[mt][nt], 0, 0, 0);
        acc[mt][nt] = __builtin_amdgcn_mfma_f32_16x16x32_bf16(afh[mt], bl, acc[mt][nt], 0, 0, 0);
        acc[mt][nt] = __builtin_amdgcn_mfma_f32_16x16x32_bf16(afl[mt], bh, acc[mt][nt], 0, 0, 0);
      }
    }
    __syncthreads();
  }
#pragma unroll
  for (int nt = 0; nt < 4; nt++) {
    int col = bn + wn + nt * 16 + fr;
    float bv = bias ? bias[col] : 0.f;
#pragma unroll
    for (int mt = 0; mt < 4; mt++) {
      int row = bm + wm + mt * 16 + fq * 4;
#pragma unroll
      for (int j = 0; j < 4; j++)
        C[(long)(row + j) * ldc + col] = acc[mt][nt][j] + bv;
    }
  }
}

// ---------------- persistent GRU layer (sync v3: per-block epoch slots) ----------------
// grid = 128 blocks x 256 threads. Block owns 4 j's. Whh slice (24 KB) in LDS.
// Per step: poll 128 epoch slots (128B apart, one writer each, NO RMW) ->
// stage h via sc0sc1 loads -> matvec -> store h sc0sc1 -> vmcnt(0)+barrier ->
// tid0 stores own epoch = t+1. All relaxed agent ops: no L2 cache maintenance.
// Epoch slot region per layer: 128 blocks * 32 ints = 4096 ints.
#define WS_ 528
#define HS_ 536
__global__ __launch_bounds__(256) void k_gru_layer(
    const float* __restrict__ xp, float* __restrict__ y,
    const float* __restrict__ Whh, const float* __restrict__ bhh,
    const float* __restrict__ hinit, long hbs, int* __restrict__ ep) {
  __shared__ float wls[12 * WS_];
  __shared__ float hls[16 * HS_];
  __shared__ float bls[12];
  __shared__ int wok[2];
  int tid = threadIdx.x;
  int j0 = blockIdx.x * 4;
  int jj = tid >> 6, b = (tid >> 2) & 15, kq = tid & 3;

  for (int r = 0; r < 12; r++) {
    int jjr = r / 3, g = r % 3;
    const float* src = Whh + (long)(g * 512 + j0 + jjr) * 512;
    int k = tid * 2;
    float2 v = *(const float2*)(src + k);
    int dst = r * WS_ + (k >> 7) * 132 + (k & 127);
    wls[dst] = v.x;
    wls[dst + 1] = v.y;
  }
  if (tid < 12) bls[tid] = bhh[(tid % 3) * 512 + j0 + tid / 3];

  int hbase = b * HS_ + kq * 132;
  int wb0 = (jj * 3 + 0) * WS_ + kq * 132;
  int wb1 = (jj * 3 + 1) * WS_ + kq * 132;
  int wb2 = (jj * 3 + 2) * WS_ + kq * 132;
  int j = j0 + jj;
  int hjj = b * HS_ + (j >> 7) * 132 + (j & 127);

  __syncthreads();  // wls/bls ready; also first-iteration hls ordering

  for (int t = 0; t < 256; t++) {
    // ---- prefetch xp gate inputs (independent of h) ----
    float xr = 0.f, xz = 0.f, xn = 0.f;
    if (kq == 0) {
      const float* xpt = xp + ((long)b * 256 + t) * 1536;
      xr = xpt[j]; xz = xpt[j + 512]; xn = xpt[j + 1024];
    }
    // ---- wait until all blocks published h(t-1): ep[*] >= t ----
    if (t > 0) {
      while (true) {
        int myok = 1;
        if (tid < 128) {
          int e;
          asm volatile("global_load_dword %0, %1, off sc0 sc1"
                       : "=v"(e) : "v"(ep + tid * 32));
          asm volatile("s_waitcnt vmcnt(0)" ::: "memory");
          myok = (e >= t);
        }
        unsigned long long ball = __ballot(myok);
        if ((tid & 63) == 0) wok[tid >> 6] = (ball == ~0ull) ? 1 : 0;
        __syncthreads();
        if (wok[0] && wok[1]) break;  // waves 2,3 are all-ok by construction
        __builtin_amdgcn_s_sleep(2);
        __syncthreads();
      }
    }
    // ---- stage h(t-1) [16][512] via coherent 16B loads ----
    f32x4 hv4[8];
#pragma unroll
    for (int i = 0; i < 8; i++) {
      int f4 = i * 256 + tid;          // 2048 float4 = 32 KB
      int bb = f4 >> 7, rem4 = f4 & 127;
      const float* src = (t == 0) ? (hinit + (long)bb * hbs + rem4 * 4)
                                  : (y + ((long)bb * 256 + (t - 1)) * 512 + rem4 * 4);
      hv4[i] = load_f4_coh(src);
    }
    asm volatile("s_waitcnt vmcnt(0)" ::: "memory");
    __builtin_amdgcn_sched_barrier(0);
#pragma unroll
    for (int i = 0; i < 8; i++) {
      int f4 = i * 256 + tid;
      int bb = f4 >> 7, rem = (f4 & 127) * 4;
      *(f32x4*)&hls[bb * HS_ + (rem >> 7) * 132 + (rem & 127)] = hv4[i];
    }
    __syncthreads();
    // ---- matvec: 3 gates x 128 MACs per thread ----
    float a0 = 0.f, a1 = 0.f, a2 = 0.f;
#pragma unroll 8
    for (int kc = 0; kc < 128; kc += 4) {
      float4 hv = *(const float4*)&hls[hbase + kc];
      float4 w0 = *(const float4*)&wls[wb0 + kc];
      float4 w1 = *(const float4*)&wls[wb1 + kc];
      float4 w2 = *(const float4*)&wls[wb2 + kc];
      a0 += hv.x * w0.x + hv.y * w0.y + hv.z * w0.z + hv.w * w0.w;
      a1 += hv.x * w1.x + hv.y * w1.y + hv.z * w1.z + hv.w * w1.w;
      a2 += hv.x * w2.x + hv.y * w2.y + hv.z * w2.z + hv.w * w2.w;
    }
    a0 += __shfl_xor(a0, 1); a0 += __shfl_xor(a0, 2);
    a1 += __shfl_xor(a1, 1); a1 += __shfl_xor(a1, 2);
    a2 += __shfl_xor(a2, 1); a2 += __shfl_xor(a2, 2);
    if (kq == 0) {
      float hr = a0 + bls[jj * 3 + 0];
      float hz = a1 + bls[jj * 3 + 1];
      float hn = a2 + bls[jj * 3 + 2];
      float r = 1.f / (1.f + __expf(-(xr + hr)));
      float z = 1.f / (1.f + __expf(-(xz + hz)));
      float n = tanhf(xn + r * hn);
      float hp = hls[hjj];
      float hv = (1.f - z) * n + z * hp;
      __hip_atomic_store(&y[((long)b * 256 + t) * 512 + j], hv,
                         __ATOMIC_RELAXED, __HIP_MEMORY_SCOPE_AGENT);
    }
    // ---- publish: own stores acked at MALL, then epoch store ----
    asm volatile("s_waitcnt vmcnt(0)" ::: "memory");
    __syncthreads();  // all lanes' h stores acked
    if (tid == 0)
      __hip_atomic_store(ep + blockIdx.x * 32, t + 1,
                         __ATOMIC_RELAXED, __HIP_MEMORY_SCOPE_AGENT);
  }
}

// ---------------- row softmax over 256 ----------------
__global__ __launch_bounds__(256) void k_softmax(float* __restrict__ p) {
  long row = blockIdx.x;
  int tid = threadIdx.x;
  float* pr = p + row * 256;
  float v = pr[tid];
  float m = v;
#pragma unroll
  for (int off = 32; off >= 1; off >>= 1) m = fmaxf(m, __shfl_xor(m, off));
  __shared__ float wmax[4];
  __shared__ float wsum[4];
  int wv = tid >> 6, ln = tid & 63;
  if (ln == 0) wmax[wv] = m;
  __syncthreads();
  m = fmaxf(fmaxf(wmax[0], wmax[1]), fmaxf(wmax[2], wmax[3]));
  float e = expf(v - m);
  float s = e;
#pragma unroll
  for (int off = 32; off >= 1; off >>= 1) s += __shfl_xor(s, off);
  if (ln == 0) wsum[wv] = s;
  __syncthreads();
  s = wsum[0] + wsum[1] + wsum[2] + wsum[3];
  pr[tid] = e / s;
}

extern "C" void kernel_launch(void* const* d_in, const int* in_sizes, int n_in,
                              void* d_out, int out_size, void* d_ws, size_t ws_size,
                              hipStream_t stream) {
  const int* en_sen = (const int*)d_in[0];
  const int* zh_sen = (const int*)d_in[1];
  const float* en_emb = (const float*)d_in[2];
  const float* zh_emb = (const float*)d_in[3];
  const float* h0 = (const float*)d_in[4];
  const float* Wih_e0 = (const float*)d_in[5];
  const float* Whh_e0 = (const float*)d_in[6];
  const float* bih_e0 = (const float*)d_in[7];
  const float* bhh_e0 = (const float*)d_in[8];
  const float* Wih_e1 = (const float*)d_in[9];
  const float* Whh_e1 = (const float*)d_in[10];
  const float* bih_e1 = (const float*)d_in[11];
  const float* bhh_e1 = (const float*)d_in[12];
  const float* Wih_d0 = (const float*)d_in[13];
  const float* Whh_d0 = (const float*)d_in[14];
  const float* bih_d0 = (const float*)d_in[15];
  const float* bhh_d0 = (const float*)d_in[16];
  const float* Wih_d1 = (const float*)d_in[17];
  const float* Whh_d1 = (const float*)d_in[18];
  const float* bih_d1 = (const float*)d_in[19];
  const float* bhh_d1 = (const float*)d_in[20];
  const float* fcW = (const float*)d_in[21];
  const float* fcb = (const float*)d_in[22];
  float* out = (float*)d_out;

  // FC inputs must not alias d_out -> d_ws (16 MiB).
  float* decOut = (float*)d_ws;
  float* ctx = decOut + 2097152;

  // d_out scratch: epoch slots [4 layers][128 blocks][32 ints] = 64 KB, then buffers.
  int* flags = (int*)d_out;              // 16384 ints
  float* bufE = (float*)d_out + 16384;   // ex / zx  [B*256*1024]
  float* xp = bufE + 4194304;            // [B*256*1536]
  float* bufY = xp + 6291456;            // y_e0 then y_d0
  float* enOut = bufY + 2097152;         // y_e1
  float* scT = enOut + 2097152;          // scores/attn [B,T,S]
  float* enOutT = scT + 1048576;         // [B,512,256]

  hipMemsetAsync(flags, 0, 16384 * sizeof(int), stream);

  dim3 tb(32, 8);

  // ---------------- encoder ----------------
  k_embed_enc<<<B_ * S_, 256, 0, stream>>>(en_sen, en_emb, bufE);
  k_gemm_mfma_nt<<<dim3(G_ / 128, (B_ * S_) / 128, 1), 256, 0, stream>>>(
      bufE, E_, nullptr, 0, E_, Wih_e0, E_, bih_e0, xp, G_, E_);
  k_gru_layer<<<128, 256, 0, stream>>>(xp, bufY, Whh_e0, bhh_e0, h0, (long)H_, flags);
  k_gemm_mfma_nt<<<dim3(G_ / 128, (B_ * S_) / 128, 1), 256, 0, stream>>>(
      bufY, H_, nullptr, 0, H_, Wih_e1, H_, bih_e1, xp, G_, H_);
  k_gru_layer<<<128, 256, 0, stream>>>(xp, enOut, Whh_e1, bhh_e1, h0 + B_ * H_, (long)H_,
                                       flags + 4096);

  // ---------------- decoder ----------------
  k_embed_dec<<<B_ * T_, 256, 0, stream>>>(zh_sen, zh_emb, bufE);
  k_gemm_mfma_nt<<<dim3(G_ / 128, (B_ * T_) / 128, 1), 256, 0, stream>>>(
      bufE, E_, nullptr, 0, E_, Wih_d0, E_, bih_d0, xp, G_, E_);
  k_gru_layer<<<128, 256, 0, stream>>>(xp, bufY, Whh_d0, bhh_d0, bufY + 255 * H_,
                                       (long)(256 * H_), flags + 8192);
  k_gemm_mfma_nt<<<dim3(G_ / 128, (B_ * T_) / 128, 1), 256, 0, stream>>>(
      bufY, H_, nullptr, 0, H_, Wih_d1, H_, bih_d1, xp, G_, H_);
  k_gru_layer<<<128, 256, 0, stream>>>(xp, decOut, Whh_d1, bhh_d1, enOut + 255 * H_,
                                       (long)(256 * H_), flags + 12288);

  // ---------------- attention ----------------
  k_gemm_nt<<<dim3(S_ / 128, T_ / 128, B_), 256, 0, stream>>>(
      decOut, H_, nullptr, 0, H_, enOut, H_, nullptr, scT, S_, H_,
      (long)T_ * H_, (long)S_ * H_, (long)T_ * S_);
  k_softmax<<<B_ * T_, 256, 0, stream>>>(scT);
  k_transpose<<<dim3(16, 8, B_), tb, 0, stream>>>(enOut, enOutT, 256, 512);
  k_gemm_nt<<<dim3(H_ / 128, T_ / 128, B_), 256, 0, stream>>>(
      scT, S_, nullptr, 0, S_, enOutT, S_, nullptr, ctx, H_, S_,
      (long)T_ * S_, (long)H_ * S_, (long)T_ * H_);

  // ---------------- final FC ----------------
  k_gemm_mfma_nt<<<dim3(V_ / 128, (B_ * T_) / 128, 1), 256, 0, stream>>>(
      decOut, H_, ctx, H_, H_, fcW, E_, fcb, out, V_, E_);
}